// Round 2
// baseline (419.481 us; speedup 1.0000x reference)
//
#include <hip/hip_runtime.h>
#include <hip/hip_bf16.h>

// Dequant: out[r][c] = (float)q[r][c] * row_stats[r] * (1/127)
// ROWS=COLS=8192, memory-bound streaming (537 MB traffic, floor ~85us @6.3TB/s).
//
// R2: one block per row (8192 blocks), 8 unrolled int4->float4 chunks per
// thread for ILP; non-temporal load/store (no reuse, working set > L3);
// row scale is a single scalar load per block.

#define COLS   8192
#define INV127 (1.0f / 127.0f)

typedef int   iv4 __attribute__((ext_vector_type(4)));
typedef float fv4 __attribute__((ext_vector_type(4)));

__global__ __launch_bounds__(256) void
bnb_dequant_kernel(const iv4* __restrict__ q,
                   const float* __restrict__ stats,
                   fv4* __restrict__ out) {
    const int row = blockIdx.x;                      // block-uniform
    const float scale = stats[row] * INV127;         // s_load + s_mul

    const int n4row = COLS / 4;                      // 2048 int4 per row
    const iv4* qrow = q   + (size_t)row * n4row;
    fv4*       orow = out + (size_t)row * n4row;
    const int t = threadIdx.x;

#pragma unroll
    for (int j = 0; j < 8; ++j) {                    // 8 * 256 = 2048
        const int i = j * 256 + t;
        iv4 v = __builtin_nontemporal_load(&qrow[i]);
        fv4 o;
        o.x = (float)v.x * scale;
        o.y = (float)v.y * scale;
        o.z = (float)v.z * scale;
        o.w = (float)v.w * scale;
        __builtin_nontemporal_store(o, &orow[i]);
    }
}

extern "C" void kernel_launch(void* const* d_in, const int* in_sizes, int n_in,
                              void* d_out, int out_size, void* d_ws, size_t ws_size,
                              hipStream_t stream) {
    const iv4*   q     = (const iv4*)d_in[0];
    const float* stats = (const float*)d_in[1];
    fv4*         out   = (fv4*)d_out;

    const int rows = out_size / COLS;                // 8192
    bnb_dequant_kernel<<<rows, 256, 0, stream>>>(q, stats, out);
}